// Round 2
// baseline (571.781 us; speedup 1.0000x reference)
//
#include <hip/hip_runtime.h>
#include <stdint.h>

typedef __attribute__((ext_vector_type(8))) short bf16x8;    // 8 bf16 in 4 VGPRs
typedef __attribute__((ext_vector_type(16))) float f32x16;   // 32x32 MFMA C/D frag
typedef __attribute__((ext_vector_type(4))) unsigned short u16x4;

__device__ __forceinline__ unsigned short f2bf(float f) {
  uint32_t u = __builtin_bit_cast(uint32_t, f);
  uint32_t r = (u + 0x7FFFu + ((u >> 16) & 1u)) >> 16;  // round-to-nearest-even
  return (unsigned short)r;
}

// ---------------- Kernel 1: x fp32 -> bf16 ----------------
__global__ __launch_bounds__(256) void cvt_x_kernel(const float4* __restrict__ x,
                                                    u16x4* __restrict__ xb, int n4) {
  int i = blockIdx.x * 256 + threadIdx.x;
  if (i >= n4) return;
  float4 v = x[i];
  u16x4 o;
  o.x = f2bf(v.x); o.y = f2bf(v.y); o.z = f2bf(v.z); o.w = f2bf(v.w);
  xb[i] = o;
}

// ---------------- Kernel 2: gather-dequant into B^T [N][K] bf16 ----------------
// thread -> (k, 16-group chunk): reads its own full 64B label line (4 x int4),
// so label traffic is 1x (was 16x line amplification with one-label-per-thread).
// Stores keep k as the wave-fast index -> each store instr = 128B contiguous.
__global__ __launch_bounds__(256) void dequant_kernel(const float* __restrict__ centroids,
                                                      const int* __restrict__ labels,
                                                      const float* __restrict__ scale,
                                                      unsigned short* __restrict__ Bt,
                                                      int K, int G) {
  const int k  = blockIdx.x * 256 + threadIdx.x;   // 0..K-1
  const int gc = blockIdx.y;                        // 0..G/16-1
  const float rs = 1.0f / fmaxf(scale[k], 1e-8f);
  const int4* lp = (const int4*)(labels + (size_t)k * G + gc * 16);

#pragma unroll
  for (int j = 0; j < 4; ++j) {
    int4 lv = lp[j];
    int labs[4] = {lv.x, lv.y, lv.z, lv.w};
#pragma unroll
    for (int q = 0; q < 4; ++q) {
      const int g = gc * 16 + j * 4 + q;
      const float4* c = (const float4*)(centroids + (size_t)labs[q] * 8);
      float4 c0 = c[0], c1 = c[1];
      size_t base = (size_t)(g * 8) * (size_t)K + (size_t)k;
      Bt[base + 0 * (size_t)K] = f2bf(c0.x * rs);
      Bt[base + 1 * (size_t)K] = f2bf(c0.y * rs);
      Bt[base + 2 * (size_t)K] = f2bf(c0.z * rs);
      Bt[base + 3 * (size_t)K] = f2bf(c0.w * rs);
      Bt[base + 4 * (size_t)K] = f2bf(c1.x * rs);
      Bt[base + 5 * (size_t)K] = f2bf(c1.y * rs);
      Bt[base + 6 * (size_t)K] = f2bf(c1.z * rs);
      Bt[base + 7 * (size_t)K] = f2bf(c1.w * rs);
    }
  }
}

// ---------------- Kernel 3: bf16 GEMM (A[M][K] x Bt[N][K]) + bias, fp32 out ----
// 128x128 block tile, 4 waves in 2x2, each wave 64x64 as 2x2 of 32x32x16 MFMA.
// 32x32x16 runs at 4061 FLOP/cyc vs 3378 for 16x16x32 (m119) -> fewer matrix-
// pipe cycles per K-iter (64.6 vs 77.6) with identical LDS/staging traffic.
#define BM 128
#define BN 128
#define BK 32

__global__ __launch_bounds__(256, 3) void gemm_bias_kernel(
    const unsigned short* __restrict__ A,   // [M][K] bf16
    const unsigned short* __restrict__ B,   // [N][K] bf16 (B^T layout)
    const float* __restrict__ bias,         // [N]
    float* __restrict__ C,                  // [M][N] fp32
    int M, int N, int K) {
  __shared__ __align__(16) unsigned short sA[BM * BK];  // 8 KB
  __shared__ __align__(16) unsigned short sB[BN * BK];  // 8 KB

  const int tid   = threadIdx.x;
  const int w     = tid >> 6;        // wave 0..3
  const int lane  = tid & 63;
  const int l31   = lane & 31;
  const int khalf = lane >> 5;       // 0..1
  const int wm    = w >> 1;          // 2x2 wave grid, each wave 64x64
  const int wn    = w & 1;

  const int m0 = blockIdx.y * BM;
  const int n0 = blockIdx.x * BN;

  // staging chunks: tile = 512 x 16B chunks per operand; chunk c -> row c>>2,
  // k-quarter c&3. 256 threads x 2 rounds. LDS dest = wave-uniform base + lane*16.
  const int c0 = w * 64 + lane;
  const int c1 = 256 + c0;

  const unsigned short* gA0 = A + (size_t)(m0 + (c0 >> 2)) * K + (c0 & 3) * 8;
  const unsigned short* gA1 = A + (size_t)(m0 + (c1 >> 2)) * K + (c1 & 3) * 8;
  const unsigned short* gB0 = B + (size_t)(n0 + (c0 >> 2)) * K + (c0 & 3) * 8;
  const unsigned short* gB1 = B + (size_t)(n0 + (c1 >> 2)) * K + (c1 & 3) * 8;

  unsigned short* lA0 = sA + (w * 64) * 8;
  unsigned short* lA1 = sA + (256 + w * 64) * 8;
  unsigned short* lB0 = sB + (w * 64) * 8;
  unsigned short* lB1 = sB + (256 + w * 64) * 8;

  f32x16 acc[2][2];
#pragma unroll
  for (int i = 0; i < 2; ++i)
#pragma unroll
    for (int j = 0; j < 2; ++j)
      acc[i][j] = (f32x16)(0.f);

  const int nIter = K / BK;
  for (int it = 0; it < nIter; ++it) {
    __builtin_amdgcn_global_load_lds((__attribute__((address_space(1))) void*)gA0,
                                     (__attribute__((address_space(3))) void*)lA0, 16, 0, 0);
    __builtin_amdgcn_global_load_lds((__attribute__((address_space(1))) void*)gA1,
                                     (__attribute__((address_space(3))) void*)lA1, 16, 0, 0);
    __builtin_amdgcn_global_load_lds((__attribute__((address_space(1))) void*)gB0,
                                     (__attribute__((address_space(3))) void*)lB0, 16, 0, 0);
    __builtin_amdgcn_global_load_lds((__attribute__((address_space(1))) void*)gB1,
                                     (__attribute__((address_space(3))) void*)lB1, 16, 0, 0);
    gA0 += BK; gA1 += BK; gB0 += BK; gB1 += BK;

    __syncthreads();  // drains vmcnt(0): staging complete for all waves

#pragma unroll
    for (int s = 0; s < 2; ++s) {    // two K=16 steps per BK=32 tile
      bf16x8 af[2], bfr[2];
      // A-frag (32x32x16): lane holds A[m = l31][k = khalf*8 + j]
#pragma unroll
      for (int mi = 0; mi < 2; ++mi)
        af[mi] = *(const bf16x8*)(sA + (wm * 64 + mi * 32 + l31) * BK + s * 16 + khalf * 8);
#pragma unroll
      for (int ni = 0; ni < 2; ++ni)
        bfr[ni] = *(const bf16x8*)(sB + (wn * 64 + ni * 32 + l31) * BK + s * 16 + khalf * 8);

#pragma unroll
      for (int mi = 0; mi < 2; ++mi)
#pragma unroll
        for (int ni = 0; ni < 2; ++ni)
          acc[mi][ni] = __builtin_amdgcn_mfma_f32_32x32x16_bf16(af[mi], bfr[ni],
                                                                acc[mi][ni], 0, 0, 0);
    }

    __syncthreads();  // protect LDS from next iteration's staging
  }

  // epilogue: 32x32 C/D layout (m74/m101-verified):
  //   n = lane&31, m = (reg&3) + 8*(reg>>2) + 4*(lane>>5)
#pragma unroll
  for (int ni = 0; ni < 2; ++ni) {
    const int n = n0 + wn * 64 + ni * 32 + l31;
    const float bv = bias[n];
#pragma unroll
    for (int mi = 0; mi < 2; ++mi) {
      const int mb = m0 + wm * 64 + mi * 32 + 4 * khalf;
#pragma unroll
      for (int r = 0; r < 16; ++r) {
        const int m = mb + (r & 3) + 8 * (r >> 2);
        C[(size_t)m * N + n] = acc[mi][ni][r] + bv;
      }
    }
  }
}

// ---------------- Fallback (only if ws too small): correct but slow ----------
__global__ __launch_bounds__(256) void fallback_kernel(
    const float* __restrict__ x, const float* __restrict__ centroids,
    const int* __restrict__ labels, const float* __restrict__ scale,
    const float* __restrict__ bias, float* __restrict__ out,
    int M, int N, int K, int G) {
  int idx = blockIdx.x * 256 + threadIdx.x;
  if (idx >= M * N) return;
  int m = idx / N, n = idx % N;
  float acc = 0.f;
  for (int k = 0; k < K; ++k) {
    int lab = labels[(size_t)k * G + (n >> 3)];
    float wv = centroids[(size_t)lab * 8 + (n & 7)] / fmaxf(scale[k], 1e-8f);
    acc += x[(size_t)m * K + k] * wv;
  }
  out[idx] = acc + bias[n];
}

extern "C" void kernel_launch(void* const* d_in, const int* in_sizes, int n_in,
                              void* d_out, int out_size, void* d_ws, size_t ws_size,
                              hipStream_t stream) {
  const float* x         = (const float*)d_in[0];
  const float* centroids = (const float*)d_in[1];
  const int*   labels    = (const int*)d_in[2];
  const float* scale     = (const float*)d_in[3];
  const float* bias      = (const float*)d_in[4];
  float* out = (float*)d_out;

  const int in_f  = in_sizes[3];         // 4096 (K)
  const int out_f = in_sizes[4];         // 4096 (N)
  const int M     = in_sizes[0] / in_f;  // 8192
  const int G     = in_sizes[2] / in_f;  // 512 groups per column
  const int K = in_f, N = out_f;

  size_t need = (size_t)M * K * 2 + (size_t)N * K * 2;  // ~100.7 MB
  if (ws_size < need) {
    int total = M * N;
    fallback_kernel<<<dim3((total + 255) / 256), 256, 0, stream>>>(
        x, centroids, labels, scale, bias, out, M, N, K, G);
    return;
  }

  unsigned short* Xb = (unsigned short*)d_ws;           // [M][K] bf16
  unsigned short* Bt = Xb + (size_t)M * K;              // [N][K] bf16

  int n4 = (M * K) / 4;
  cvt_x_kernel<<<dim3((n4 + 255) / 256), 256, 0, stream>>>((const float4*)x, (u16x4*)Xb, n4);
  dequant_kernel<<<dim3(K / 256, G / 16), 256, 0, stream>>>(centroids, labels, scale, Bt, K, G);
  gemm_bias_kernel<<<dim3(N / BN, M / BM), 256, 0, stream>>>(Xb, Bt, bias, out, M, N, K);
}

// Round 3
// 532.306 us; speedup vs baseline: 1.0742x; 1.0742x over previous
//
#include <hip/hip_runtime.h>
#include <stdint.h>

typedef __attribute__((ext_vector_type(8))) short bf16x8;   // 8 bf16 in 4 VGPRs
typedef __attribute__((ext_vector_type(4))) float f32x4;    // MFMA C/D frag
typedef __attribute__((ext_vector_type(4))) unsigned short u16x4;

__device__ __forceinline__ unsigned short f2bf(float f) {
  uint32_t u = __builtin_bit_cast(uint32_t, f);
  uint32_t r = (u + 0x7FFFu + ((u >> 16) & 1u)) >> 16;  // round-to-nearest-even
  return (unsigned short)r;
}

// ---------------- Fused prep: dequant blocks first, then cvt blocks ----------
// Dequant: thread -> (k-pair p, 4 groups). Reads labels rows 2p,2p+1 (int4 each),
// 16 independent float4 centroid gathers, writes 32 packed u32 (bf16 pair for
// k=2p,2p+1) -> 4B/lane, 256B/wave contiguous stores.
// Cvt: x fp32 -> bf16, float4 in / u16x4 out.
// Fusing lets the latency-bound dequant waves overlap the BW-bound cvt waves.
__global__ __launch_bounds__(256) void prep_kernel(
    const float4* __restrict__ x, u16x4* __restrict__ xb, int n4,
    const float* __restrict__ centroids, const int* __restrict__ labels,
    const float* __restrict__ scale, uint32_t* __restrict__ BtP,
    int K, int G, int dqBlocksX, int dqBlocks) {
  const int bid = blockIdx.x;
  if (bid < dqBlocks) {
    const int bx = bid % dqBlocksX;           // kpair block (pow2 count)
    const int by = bid / dqBlocksX;           // group quad
    const int p  = bx * 256 + threadIdx.x;    // kpair index, 0..K/2-1
    const int k0 = 2 * p;
    const int g0 = by * 4;
    const int Kh = K >> 1;

    const float rs0 = 1.0f / fmaxf(scale[k0], 1e-8f);
    const float rs1 = 1.0f / fmaxf(scale[k0 + 1], 1e-8f);
    const int4 La = *(const int4*)(labels + (size_t)k0 * G + g0);
    const int4 Lb = *(const int4*)(labels + (size_t)(k0 + 1) * G + g0);
    const int la[4] = {La.x, La.y, La.z, La.w};
    const int lb[4] = {Lb.x, Lb.y, Lb.z, Lb.w};

    float4 a0[4], a1[4], b0[4], b1[4];
#pragma unroll
    for (int g = 0; g < 4; ++g) {             // 16 independent gathers -> MLP
      const float4* pa = (const float4*)(centroids + (size_t)la[g] * 8);
      const float4* pb = (const float4*)(centroids + (size_t)lb[g] * 8);
      a0[g] = pa[0]; a1[g] = pa[1];
      b0[g] = pb[0]; b1[g] = pb[1];
    }

#pragma unroll
    for (int g = 0; g < 4; ++g) {
      const float fa[8] = {a0[g].x, a0[g].y, a0[g].z, a0[g].w,
                           a1[g].x, a1[g].y, a1[g].z, a1[g].w};
      const float fb[8] = {b0[g].x, b0[g].y, b0[g].z, b0[g].w,
                           b1[g].x, b1[g].y, b1[g].z, b1[g].w};
      const size_t nbase = (size_t)((g0 + g) * 8) * (size_t)Kh + (size_t)p;
#pragma unroll
      for (int j = 0; j < 8; ++j) {
        uint32_t v = (uint32_t)f2bf(fa[j] * rs0) |
                     ((uint32_t)f2bf(fb[j] * rs1) << 16);
        BtP[nbase + (size_t)j * Kh] = v;
      }
    }
  } else {
    const int i = (bid - dqBlocks) * 256 + threadIdx.x;
    if (i >= n4) return;
    float4 v = x[i];
    u16x4 o;
    o.x = f2bf(v.x); o.y = f2bf(v.y); o.z = f2bf(v.z); o.w = f2bf(v.w);
    xb[i] = o;
  }
}

// ---------------- bf16 GEMM (A[M][K] x Bt[N][K]) + bias, fp32 out ------------
// R1-verified structure: 128x128 tile, 4 waves 2x2, 4x4 of 16x16x32 MFMA,
// global_load_lds width-16 staging, ds_read_b128 fragments. 324 us / 848 TF.
#define BM 128
#define BN 128
#define BK 32

__global__ __launch_bounds__(256, 3) void gemm_bias_kernel(
    const unsigned short* __restrict__ A,   // [M][K] bf16
    const unsigned short* __restrict__ B,   // [N][K] bf16 (B^T layout)
    const float* __restrict__ bias,         // [N]
    float* __restrict__ C,                  // [M][N] fp32
    int M, int N, int K) {
  __shared__ __align__(16) unsigned short sA[BM * BK];  // 8 KB
  __shared__ __align__(16) unsigned short sB[BN * BK];  // 8 KB

  const int tid  = threadIdx.x;
  const int w    = tid >> 6;        // wave 0..3
  const int lane = tid & 63;
  const int ln   = lane & 15;
  const int quad = lane >> 4;
  const int wm   = w >> 1;          // 2x2 wave grid, each wave 64x64
  const int wn   = w & 1;

  const int m0 = blockIdx.y * BM;
  const int n0 = blockIdx.x * BN;

  // staging: 512 x 16B chunks per operand; chunk c -> row c>>2, k-quarter c&3.
  const int c0 = w * 64 + lane;
  const int c1 = 256 + c0;

  const unsigned short* gA0 = A + (size_t)(m0 + (c0 >> 2)) * K + (c0 & 3) * 8;
  const unsigned short* gA1 = A + (size_t)(m0 + (c1 >> 2)) * K + (c1 & 3) * 8;
  const unsigned short* gB0 = B + (size_t)(n0 + (c0 >> 2)) * K + (c0 & 3) * 8;
  const unsigned short* gB1 = B + (size_t)(n0 + (c1 >> 2)) * K + (c1 & 3) * 8;

  unsigned short* lA0 = sA + (w * 64) * 8;
  unsigned short* lA1 = sA + (256 + w * 64) * 8;
  unsigned short* lB0 = sB + (w * 64) * 8;
  unsigned short* lB1 = sB + (256 + w * 64) * 8;

  f32x4 acc[4][4];
#pragma unroll
  for (int i = 0; i < 4; ++i)
#pragma unroll
    for (int j = 0; j < 4; ++j)
      acc[i][j] = (f32x4){0.f, 0.f, 0.f, 0.f};

  const int nIter = K / BK;
  for (int it = 0; it < nIter; ++it) {
    __builtin_amdgcn_global_load_lds((__attribute__((address_space(1))) void*)gA0,
                                     (__attribute__((address_space(3))) void*)lA0, 16, 0, 0);
    __builtin_amdgcn_global_load_lds((__attribute__((address_space(1))) void*)gA1,
                                     (__attribute__((address_space(3))) void*)lA1, 16, 0, 0);
    __builtin_amdgcn_global_load_lds((__attribute__((address_space(1))) void*)gB0,
                                     (__attribute__((address_space(3))) void*)lB0, 16, 0, 0);
    __builtin_amdgcn_global_load_lds((__attribute__((address_space(1))) void*)gB1,
                                     (__attribute__((address_space(3))) void*)lB1, 16, 0, 0);
    gA0 += BK; gA1 += BK; gB0 += BK; gB1 += BK;

    __syncthreads();  // drains vmcnt(0): staging complete for all waves

    bf16x8 af[4], bfr[4];
#pragma unroll
    for (int mi = 0; mi < 4; ++mi)
      af[mi] = *(const bf16x8*)(sA + (wm * 64 + mi * 16 + ln) * BK + quad * 8);
#pragma unroll
    for (int ni = 0; ni < 4; ++ni)
      bfr[ni] = *(const bf16x8*)(sB + (wn * 64 + ni * 16 + ln) * BK + quad * 8);

#pragma unroll
    for (int mi = 0; mi < 4; ++mi)
#pragma unroll
      for (int ni = 0; ni < 4; ++ni)
        acc[mi][ni] = __builtin_amdgcn_mfma_f32_16x16x32_bf16(af[mi], bfr[ni],
                                                              acc[mi][ni], 0, 0, 0);

    __syncthreads();  // protect LDS from next iteration's staging
  }

  // epilogue: C/D layout col = lane&15, row = quad*4 + reg (verified)
#pragma unroll
  for (int ni = 0; ni < 4; ++ni) {
    const int n = n0 + wn * 64 + ni * 16 + ln;
    const float bv = bias[n];
#pragma unroll
    for (int mi = 0; mi < 4; ++mi) {
      const int mb = m0 + wm * 64 + mi * 16 + quad * 4;
#pragma unroll
      for (int r = 0; r < 4; ++r)
        C[(size_t)(mb + r) * N + n] = acc[mi][ni][r] + bv;
    }
  }
}

// ---------------- Fallback (shape assumptions violated): correct but slow ----
__global__ __launch_bounds__(256) void fallback_kernel(
    const float* __restrict__ x, const float* __restrict__ centroids,
    const int* __restrict__ labels, const float* __restrict__ scale,
    const float* __restrict__ bias, float* __restrict__ out,
    int M, int N, int K, int G) {
  int idx = blockIdx.x * 256 + threadIdx.x;
  if (idx >= M * N) return;
  int m = idx / N, n = idx % N;
  float acc = 0.f;
  for (int k = 0; k < K; ++k) {
    int lab = labels[(size_t)k * G + (n >> 3)];
    float wv = centroids[(size_t)lab * 8 + (n & 7)] / fmaxf(scale[k], 1e-8f);
    acc += x[(size_t)m * K + k] * wv;
  }
  out[idx] = acc + bias[n];
}

extern "C" void kernel_launch(void* const* d_in, const int* in_sizes, int n_in,
                              void* d_out, int out_size, void* d_ws, size_t ws_size,
                              hipStream_t stream) {
  const float* x         = (const float*)d_in[0];
  const float* centroids = (const float*)d_in[1];
  const int*   labels    = (const int*)d_in[2];
  const float* scale     = (const float*)d_in[3];
  const float* bias      = (const float*)d_in[4];
  float* out = (float*)d_out;

  const int in_f  = in_sizes[3];         // 4096 (K)
  const int out_f = in_sizes[4];         // 4096 (N)
  const int M     = in_sizes[0] / in_f;  // 8192
  const int G     = in_sizes[2] / in_f;  // 512 groups per column
  const int K = in_f, N = out_f;

  size_t need = (size_t)M * K * 2 + (size_t)N * K * 2;  // ~100.7 MB
  bool ok = (ws_size >= need) && (K % 512 == 0) && (G % 4 == 0) &&
            (M % BM == 0) && (N % BN == 0) && (K % BK == 0) && (M * K % 1024 == 0);
  if (!ok) {
    int total = M * N;
    fallback_kernel<<<dim3((total + 255) / 256), 256, 0, stream>>>(
        x, centroids, labels, scale, bias, out, M, N, K, G);
    return;
  }

  unsigned short* Xb = (unsigned short*)d_ws;           // [M][K] bf16
  unsigned short* Bt = Xb + (size_t)M * K;              // [N][K] bf16

  const int n4 = (M * K) / 4;
  const int dqBlocksX = (K / 2) / 256;                  // 8
  const int dqBlocks  = dqBlocksX * (G / 4);            // 1024
  const int cvtBlocks = (n4 + 255) / 256;               // 8192
  prep_kernel<<<dim3(dqBlocks + cvtBlocks), 256, 0, stream>>>(
      (const float4*)x, (u16x4*)Xb, n4, centroids, labels, scale,
      (uint32_t*)Bt, K, G, dqBlocksX, dqBlocks);
  gemm_bias_kernel<<<dim3(N / BN, M / BM), 256, 0, stream>>>(Xb, Bt, bias, out, M, N, K);
}